// Round 2
// baseline (493.346 us; speedup 1.0000x reference)
//
#include <hip/hip_runtime.h>
#include <stdint.h>

// GraphConvolution: out[0:8192]   = deg[i]     *(adj  @ (v@Wv)) + bias
//                   out[8192:16k] = deg[8192+j]*(adjT @ (u@Wu)) + bias
// adj is 256 MiB fp32 -> memory-bound; floor = one adj read = ~41us @6.3TB/s.
// Strategy: bf16 MFMA, both passes in one launch, diagonal K-schedule so the
// two readers of each adj region touch it at the same step (L2/L3 reuse).

#define HID 64
#define IN_DIM 128
#define NROWS 8192
#define NCLS 5

typedef float f32x4 __attribute__((ext_vector_type(4)));
typedef short s16x8 __attribute__((ext_vector_type(8)));
typedef unsigned short u16;

// fp32 -> bf16 round-to-nearest-even
static __device__ __forceinline__ short f2b(float x) {
    unsigned u = __builtin_bit_cast(unsigned, x);
    return (short)((u + 0x7FFFu + ((u >> 16) & 1u)) >> 16);
}

// async global->LDS, 16B per lane; lds dst must be wave-uniform (HW adds lane*16)
static __device__ __forceinline__ void cp16(const void* g, void* l) {
    __builtin_amdgcn_global_load_lds(
        (const __attribute__((address_space(1))) void*)g,
        (__attribute__((address_space(3))) void*)l, 16, 0, 0);
}

// ---------------------------------------------------------------------------
// k_prep: W = sum_{c<=r} weight[c]; s = X @ W; store transposed bf16 [h][row]
// grid (128, 2): y=0 -> suT from u, y=1 -> svT from v. block 256.
// ---------------------------------------------------------------------------
__global__ __launch_bounds__(256, 2) void k_prep(
    const float* __restrict__ u, const float* __restrict__ v,
    const float* __restrict__ uw, const float* __restrict__ vw,
    const int* __restrict__ rp, u16* __restrict__ ws)
{
    __shared__ float W[IN_DIM * HID];   // [c][h], 32 KB
    __shared__ float X[64 * 129];       // [i][c], +1 pad -> 2-way (free) reads

    const int y = blockIdx.y;
    const float* __restrict__ src  = y ? v  : u;
    const float* __restrict__ wsrc = y ? vw : uw;
    u16* __restrict__ dstT = ws + (size_t)y * (HID * NROWS);
    const int i0 = blockIdx.x * 64;
    const int t = threadIdx.x;
    int r = *rp; if (r > NCLS - 1) r = NCLS - 1; if (r < 0) r = 0;

    for (int idx = t; idx < IN_DIM * HID; idx += 256) {
        float s = 0.f;
        for (int c = 0; c <= r; ++c) s += wsrc[c * (IN_DIM * HID) + idx];
        W[idx] = s;
    }
    // X tile: 64 rows x 128 cols = 2048 float4 loads  (R1 bug: was qq<4 ->
    // rows 32..63 left uninitialized -> NaN; must be qq<8)
    #pragma unroll
    for (int qq = 0; qq < 8; ++qq) {
        int idx = t + qq * 256;
        int row = idx >> 5, c4 = idx & 31;
        f32x4 val = *(const f32x4*)&src[(size_t)(i0 + row) * IN_DIM + c4 * 4];
        float* d = &X[row * 129 + c4 * 4];
        d[0] = val[0]; d[1] = val[1]; d[2] = val[2]; d[3] = val[3];
    }
    __syncthreads();

    const int i = t & 63, h0 = (t >> 6) * 16;  // lane=i -> coalesced stores
    float acc[16];
    #pragma unroll
    for (int k = 0; k < 16; ++k) acc[k] = 0.f;
    for (int c = 0; c < IN_DIM; ++c) {
        float uv = X[i * 129 + c];
        const f32x4* wr = (const f32x4*)&W[c * HID + h0]; // wave-uniform bcast
        f32x4 w0 = wr[0], w1 = wr[1], w2 = wr[2], w3 = wr[3];
        acc[0]  += uv * w0[0]; acc[1]  += uv * w0[1];
        acc[2]  += uv * w0[2]; acc[3]  += uv * w0[3];
        acc[4]  += uv * w1[0]; acc[5]  += uv * w1[1];
        acc[6]  += uv * w1[2]; acc[7]  += uv * w1[3];
        acc[8]  += uv * w2[0]; acc[9]  += uv * w2[1];
        acc[10] += uv * w2[2]; acc[11] += uv * w2[3];
        acc[12] += uv * w3[0]; acc[13] += uv * w3[1];
        acc[14] += uv * w3[2]; acc[15] += uv * w3[3];
    }
    #pragma unroll
    for (int hh = 0; hh < 16; ++hh)
        dstT[(size_t)(h0 + hh) * NROWS + i0 + i] = (u16)f2b(acc[hh]);
}

// ---------------------------------------------------------------------------
// k_main: grid (256, 2), block 256 (4 waves), 2 blocks/CU.
//  mode 0 (top): m = 32 adj rows  (strip bx), K over j; A = adj tile direct.
//  mode 1 (bot): m = 32 adj cols  (strip bx), K over i; A gathered transposed.
//  B operand: svT (mode0) / suT (mode1), bf16 [n=h][k], staged to LDS.
//  XOR-swizzled LDS (16B chunk ^= row) since global_load_lds forbids padding.
//  Diagonal K-schedule: top chunk=(bx/2+step)&127, bot chunk=(bx/2-step)&127
//  -> mode-0 strip bx and its transpose-partner mode-1 strips {2c,2c+1} touch
//  the same adj region at the same step (verified: c' = bx/2) => L2/L3 reuse.
// ---------------------------------------------------------------------------
__global__ __launch_bounds__(256, 2) void k_main(
    const float* __restrict__ adj, const float* __restrict__ degree,
    const float* __restrict__ bias, const u16* __restrict__ ws,
    float* __restrict__ out)
{
    __shared__ float At[2][2048];   // 8 KB/buf: mode0 [32][64], mode1 [64][32]
    __shared__ u16   Bt[2][4096];   // 8 KB/buf: [n=64][k=64]

    const int mode = blockIdx.y;
    const int bx = blockIdx.x;
    const int t = threadIdx.x;
    const int w = t >> 6, l = t & 63;
    const int q = l >> 4, l15 = l & 15;
    const int mt = w & 1;    // m-tile (16 rows) of the 32-row strip
    const int nh = w >> 1;   // n-half: n-tiles nh*2, nh*2+1
    const int m0 = bx * 32;
    const u16* __restrict__ BT = ws + (mode == 0 ? (size_t)(HID * NROWS) : 0);

    f32x4 acc[2];
    acc[0] = (f32x4){0.f, 0.f, 0.f, 0.f};
    acc[1] = (f32x4){0.f, 0.f, 0.f, 0.f};

    auto stage = [&](int step, int buf) {
        int kc = (mode == 0) ? (((bx >> 1) + step) & 127)
                             : (((bx >> 1) - step) & 127);
        int k0 = kc * 64;
        if (mode == 0) {
            // tile adj[m0+ii][k0+jj], rows of 64 floats, cg = 16B col-group
            #pragma unroll
            for (int t2 = 0; t2 < 2; ++t2) {
                int s = w * 2 + t2;
                int row = s * 4 + (l >> 4);
                int cg = (l & 15) ^ (row & 15);          // swizzle
                cp16(&adj[(size_t)(m0 + row) * NROWS + k0 + cg * 4],
                     &At[buf][s * 256]);
            }
        } else {
            // tile adj[k0+ii][m0+jj], rows of 32 floats (8 cgs)
            #pragma unroll
            for (int t2 = 0; t2 < 2; ++t2) {
                int s = w * 2 + t2;
                int row = s * 8 + (l >> 3);
                int cg = (l & 7) ^ (row & 7);
                cp16(&adj[(size_t)(k0 + row) * NROWS + m0 + cg * 4],
                     &At[buf][s * 256]);
            }
        }
        // B tile: BT[n][k0..k0+64], rows of 64 u16 (8 cgs of 8)
        #pragma unroll
        for (int t2 = 0; t2 < 2; ++t2) {
            int s = w * 2 + t2;
            int n = s * 8 + (l >> 3);
            int cg = (l & 7) ^ (n & 7);
            cp16(&BT[(size_t)n * NROWS + k0 + cg * 8], &Bt[buf][s * 512]);
        }
    };

    stage(0, 0);
    __syncthreads();
    int buf = 0;
    for (int step = 0; step < 128; ++step) {
        if (step < 127) stage(step + 1, buf ^ 1);  // prefetch overlaps compute
        const float* __restrict__ A = At[buf];
        const u16* __restrict__ B = Bt[buf];
        #pragma unroll
        for (int kh = 0; kh < 2; ++kh) {
            // A frag: A[m = l15 (+16*mt)][k = kh*32 + q*8 + j], j in 0..8
            s16x8 af;
            if (mode == 0) {
                const int ii = mt * 16 + l15;
                const int cgk = kh * 8 + q * 2;
                f32x4 f0 = *(const f32x4*)&A[ii * 64 + ((cgk    ) ^ (ii & 15)) * 4];
                f32x4 f1 = *(const f32x4*)&A[ii * 64 + ((cgk + 1) ^ (ii & 15)) * 4];
                af[0] = f2b(f0[0]); af[1] = f2b(f0[1]);
                af[2] = f2b(f0[2]); af[3] = f2b(f0[3]);
                af[4] = f2b(f1[0]); af[5] = f2b(f1[1]);
                af[6] = f2b(f1[2]); af[7] = f2b(f1[3]);
            } else {
                const int jj = mt * 16 + l15;            // m = adj column
                const int cg = jj >> 2, jr = jj & 3;
                #pragma unroll
                for (int tt = 0; tt < 8; ++tt) {
                    int ii = kh * 32 + q * 8 + tt;       // k = adj row
                    af[tt] = f2b(A[ii * 32 + ((cg ^ (ii & 7)) << 2) + jr]);
                }
            }
            #pragma unroll
            for (int nn = 0; nn < 2; ++nn) {
                int n = (nh * 2 + nn) * 16 + l15;
                int cgl = (kh * 4 + q) ^ (n & 7);
                s16x8 bf = *(const s16x8*)&B[n * 64 + cgl * 8];
                acc[nn] = __builtin_amdgcn_mfma_f32_16x16x32_bf16(af, bf, acc[nn], 0, 0, 0);
            }
        }
        __syncthreads();   // drains prefetch vmcnt + LDS reuse barrier
        buf ^= 1;
    }

    // epilogue: C/D layout col=l15, row=q*4+reg (m89-verified)
    const int obase = (mode == 0) ? 0 : NROWS;
    const float* __restrict__ degp = degree + obase;
    #pragma unroll
    for (int nn = 0; nn < 2; ++nn) {
        int n = (nh * 2 + nn) * 16 + l15;
        float bs = bias[n];
        #pragma unroll
        for (int rg = 0; rg < 4; ++rg) {
            int m = m0 + mt * 16 + q * 4 + rg;
            out[(size_t)(obase + m) * HID + n] = degp[m] * acc[nn][rg] + bs;
        }
    }
}

extern "C" void kernel_launch(void* const* d_in, const int* in_sizes, int n_in,
                              void* d_out, int out_size, void* d_ws, size_t ws_size,
                              hipStream_t stream) {
    (void)in_sizes; (void)n_in; (void)out_size; (void)ws_size;
    const float* u      = (const float*)d_in[0];
    const float* v      = (const float*)d_in[1];
    const float* adj    = (const float*)d_in[2];
    const float* degree = (const float*)d_in[3];
    const float* uw     = (const float*)d_in[4];
    const float* vw     = (const float*)d_in[5];
    const float* bias   = (const float*)d_in[6];
    const int*   rp     = (const int*)d_in[7];
    u16*   ws  = (u16*)d_ws;     // [0,1MB): suT bf16; [1MB,2MB): svT bf16
    float* out = (float*)d_out;

    k_prep<<<dim3(128, 2), 256, 0, stream>>>(u, v, uw, vw, rp, ws);
    k_main<<<dim3(256, 2), 256, 0, stream>>>(adj, degree, bias, ws, out);
}

// Round 3
// 481.970 us; speedup vs baseline: 1.0236x; 1.0236x over previous
//
#include <hip/hip_runtime.h>
#include <stdint.h>

// GraphConvolution: out[0:8192]    = deg[i]     *(adj  @ (v@Wv)) + bias
//                   out[8192:16k]  = deg[8192+j]*(adjT @ (u@Wu)) + bias
// adj is 256 MiB fp32 -> memory-bound; floor ~41us(dedup)/81us(no dedup).
// R2 post-mortem: per-step __syncthreads (vmcnt drain) -> 3000 cyc/step,
// 2 TB/s. R3: barrier-free K-loops; waves are independent 4-way K-splits;
// mode0 register-direct, mode1 per-wave LDS transpose (stride-33, fenced).

#define HID 64
#define IN_DIM 128
#define NROWS 8192
#define NCLS 5

typedef float f32x4 __attribute__((ext_vector_type(4)));
typedef short s16x8 __attribute__((ext_vector_type(8)));
typedef unsigned short u16;

static __device__ __forceinline__ short f2b(float x) {  // RNE fp32->bf16
    unsigned u = __builtin_bit_cast(unsigned, x);
    return (short)((u + 0x7FFFu + ((u >> 16) & 1u)) >> 16);
}

// ---------------------------------------------------------------------------
// k_prep: W = sum_{c<=r} weight[c]; s = X @ W; store transposed bf16 [h][row]
// grid (128, 2): y=0 -> suT (from u), y=1 -> svT (from v). block 256.
// ---------------------------------------------------------------------------
__global__ __launch_bounds__(256, 2) void k_prep(
    const float* __restrict__ u, const float* __restrict__ v,
    const float* __restrict__ uw, const float* __restrict__ vw,
    const int* __restrict__ rp, u16* __restrict__ ws)
{
    __shared__ float W[IN_DIM * HID];
    __shared__ float X[64 * 129];

    const int y = blockIdx.y;
    const float* __restrict__ src  = y ? v  : u;
    const float* __restrict__ wsrc = y ? vw : uw;
    u16* __restrict__ dstT = ws + (size_t)y * (HID * NROWS);
    const int i0 = blockIdx.x * 64;
    const int t = threadIdx.x;
    int r = *rp; if (r > NCLS - 1) r = NCLS - 1; if (r < 0) r = 0;

    for (int idx = t; idx < IN_DIM * HID; idx += 256) {
        float s = 0.f;
        for (int c = 0; c <= r; ++c) s += wsrc[c * (IN_DIM * HID) + idx];
        W[idx] = s;
    }
    #pragma unroll
    for (int qq = 0; qq < 8; ++qq) {       // 64 rows x 32 float4 = 2048
        int idx = t + qq * 256;
        int row = idx >> 5, c4 = idx & 31;
        f32x4 val = *(const f32x4*)&src[(size_t)(i0 + row) * IN_DIM + c4 * 4];
        float* d = &X[row * 129 + c4 * 4];
        d[0] = val[0]; d[1] = val[1]; d[2] = val[2]; d[3] = val[3];
    }
    __syncthreads();

    const int i = t & 63, h0 = (t >> 6) * 16;
    float acc[16];
    #pragma unroll
    for (int k = 0; k < 16; ++k) acc[k] = 0.f;
    for (int c = 0; c < IN_DIM; ++c) {
        float uv = X[i * 129 + c];
        const f32x4* wr = (const f32x4*)&W[c * HID + h0];
        f32x4 w0 = wr[0], w1 = wr[1], w2 = wr[2], w3 = wr[3];
        acc[0]  += uv * w0[0]; acc[1]  += uv * w0[1];
        acc[2]  += uv * w0[2]; acc[3]  += uv * w0[3];
        acc[4]  += uv * w1[0]; acc[5]  += uv * w1[1];
        acc[6]  += uv * w1[2]; acc[7]  += uv * w1[3];
        acc[8]  += uv * w2[0]; acc[9]  += uv * w2[1];
        acc[10] += uv * w2[2]; acc[11] += uv * w2[3];
        acc[12] += uv * w3[0]; acc[13] += uv * w3[1];
        acc[14] += uv * w3[2]; acc[15] += uv * w3[3];
    }
    #pragma unroll
    for (int hh = 0; hh < 16; ++hh)
        dstT[(size_t)(h0 + hh) * NROWS + i0 + i] = (u16)f2b(acc[hh]);
}

// ---------------------------------------------------------------------------
// k_main: grid (256, 2), block 256 = 4 waves. Block bx = one 32-wide strip
// (rows for mode0, cols for mode1); wave w = K-quarter [w*2048,(w+1)*2048).
// No barriers in the K-loop. Diagonal chunk order keeps the transpose
// partners' adj reads temporally aligned for L2/L3 dedup (tau* = b-a mod 32).
// End: LDS reduce of 4 partials, scale by degree, + bias, store.
// ---------------------------------------------------------------------------
__global__ __launch_bounds__(256, 2) void k_main(
    const float* __restrict__ adj, const float* __restrict__ degree,
    const float* __restrict__ bias, const u16* __restrict__ ws,
    float* __restrict__ out)
{
    __shared__ float S[4][64 * 33];   // per-wave: transpose tile / partials

    const int mode = blockIdx.y;
    const int bx = blockIdx.x;
    const int t = threadIdx.x;
    const int w = t >> 6, l = t & 63;
    const int q = l >> 4, l15 = l & 15;
    const int m0 = bx * 32;
    const unsigned a = (unsigned)(bx >> 1);        // 64-wide chunk index
    const int kbase = w * 2048;
    const u16* __restrict__ BT = ws + (mode == 0 ? (size_t)(HID * NROWS) : 0);

    f32x4 acc[2][4];
    #pragma unroll
    for (int i = 0; i < 2; ++i)
        #pragma unroll
        for (int j = 0; j < 4; ++j) acc[i][j] = (f32x4){0.f, 0.f, 0.f, 0.f};

    if (mode == 0) {
        // ---- top: C[m=row][n=h] = adj[row][:] . sv[:][h], reg-direct ----
        const float* __restrict__ ap0 = adj + (size_t)(m0 + l15) * NROWS;
        const float* __restrict__ ap1 = ap0 + (size_t)16 * NROWS;
        for (int tau = 0; tau < 32; ++tau) {
            const int k0 = kbase + (int)(((a + tau) & 31u) << 6);
            #pragma unroll
            for (int kh = 0; kh < 2; ++kh) {
                const int k = k0 + kh * 32 + q * 8;
                f32x4 a00 = *(const f32x4*)(ap0 + k);
                f32x4 a01 = *(const f32x4*)(ap0 + k + 4);
                f32x4 a10 = *(const f32x4*)(ap1 + k);
                f32x4 a11 = *(const f32x4*)(ap1 + k + 4);
                s16x8 bf[4];
                #pragma unroll
                for (int nn = 0; nn < 4; ++nn)
                    bf[nn] = *(const s16x8*)(BT + (size_t)(nn * 16 + l15) * NROWS + k);
                s16x8 af0, af1;
                af0[0]=f2b(a00[0]); af0[1]=f2b(a00[1]); af0[2]=f2b(a00[2]); af0[3]=f2b(a00[3]);
                af0[4]=f2b(a01[0]); af0[5]=f2b(a01[1]); af0[6]=f2b(a01[2]); af0[7]=f2b(a01[3]);
                af1[0]=f2b(a10[0]); af1[1]=f2b(a10[1]); af1[2]=f2b(a10[2]); af1[3]=f2b(a10[3]);
                af1[4]=f2b(a11[0]); af1[5]=f2b(a11[1]); af1[6]=f2b(a11[2]); af1[7]=f2b(a11[3]);
                #pragma unroll
                for (int nn = 0; nn < 4; ++nn) {
                    acc[0][nn] = __builtin_amdgcn_mfma_f32_16x16x32_bf16(af0, bf[nn], acc[0][nn], 0, 0, 0);
                    acc[1][nn] = __builtin_amdgcn_mfma_f32_16x16x32_bf16(af1, bf[nn], acc[1][nn], 0, 0, 0);
                }
            }
        }
    } else {
        // ---- bot: C[m=col j][n=h] = sum_i adj[i][j]*su[i][h]; per-wave
        // LDS transpose tile adj[i0..i0+64][j0..j0+32], stride 33 ----
        float* __restrict__ T = S[w];
        const int wr_r = l >> 3;            // row within 8-row group
        const int wr_c = (l & 7) * 4;       // col within 32
        const float* __restrict__ cb = adj + m0 + wr_c;
        for (int tau = 0; tau < 32; ++tau) {
            const int i0 = kbase + (int)(((a - tau) & 31u) << 6);
            f32x4 tr[8];
            #pragma unroll
            for (int c = 0; c < 8; ++c)
                tr[c] = *(const f32x4*)(cb + (size_t)(i0 + c * 8 + wr_r) * NROWS);
            #pragma unroll
            for (int c = 0; c < 8; ++c) {
                float* d = &T[(c * 8 + wr_r) * 33 + wr_c];
                d[0] = tr[c][0]; d[1] = tr[c][1]; d[2] = tr[c][2]; d[3] = tr[c][3];
            }
            asm volatile("s_waitcnt lgkmcnt(0)" ::: "memory");  // in-wave fence
            #pragma unroll
            for (int kh = 0; kh < 2; ++kh) {
                const int kk = i0 + kh * 32 + q * 8;
                s16x8 bf[4];
                #pragma unroll
                for (int nn = 0; nn < 4; ++nn)
                    bf[nn] = *(const s16x8*)(BT + (size_t)(nn * 16 + l15) * NROWS + kk);
                s16x8 af[2];
                #pragma unroll
                for (int mt = 0; mt < 2; ++mt) {
                    const int j = mt * 16 + l15;
                    #pragma unroll
                    for (int tt = 0; tt < 8; ++tt)
                        af[mt][tt] = f2b(T[(kh * 32 + q * 8 + tt) * 33 + j]);
                }
                #pragma unroll
                for (int nn = 0; nn < 4; ++nn) {
                    acc[0][nn] = __builtin_amdgcn_mfma_f32_16x16x32_bf16(af[0], bf[nn], acc[0][nn], 0, 0, 0);
                    acc[1][nn] = __builtin_amdgcn_mfma_f32_16x16x32_bf16(af[1], bf[nn], acc[1][nn], 0, 0, 0);
                }
            }
            asm volatile("" ::: "memory");  // keep next tau's writes after reads
        }
    }

    // partials -> own LDS region (C/D layout: col=l15, row=q*4+reg; m89)
    asm volatile("" ::: "memory");
    {
        float* __restrict__ P = S[w];
        #pragma unroll
        for (int mt = 0; mt < 2; ++mt)
            #pragma unroll
            for (int nn = 0; nn < 4; ++nn)
                #pragma unroll
                for (int rg = 0; rg < 4; ++rg)
                    P[(mt * 16 + q * 4 + rg) * 64 + nn * 16 + l15] = acc[mt][nn][rg];
    }
    __syncthreads();

    // reduce 4 K-splits, scale + bias, coalesced f32x4 stores
    const int e0 = t * 8;
    const int m = e0 >> 6, n = e0 & 63;
    f32x4 s0 = (f32x4){0.f,0.f,0.f,0.f}, s1 = s0;
    #pragma unroll
    for (int ww = 0; ww < 4; ++ww) {
        s0 += *(const f32x4*)&S[ww][e0];
        s1 += *(const f32x4*)&S[ww][e0 + 4];
    }
    const int grow = (mode ? NROWS : 0) + m0 + m;
    const float d = degree[grow];
    f32x4 b0 = *(const f32x4*)&bias[n];
    f32x4 b1 = *(const f32x4*)&bias[n + 4];
    f32x4 o0 = d * s0 + b0;
    f32x4 o1 = d * s1 + b1;
    *(f32x4*)&out[(size_t)grow * HID + n]     = o0;
    *(f32x4*)&out[(size_t)grow * HID + n + 4] = o1;
}

extern "C" void kernel_launch(void* const* d_in, const int* in_sizes, int n_in,
                              void* d_out, int out_size, void* d_ws, size_t ws_size,
                              hipStream_t stream) {
    (void)in_sizes; (void)n_in; (void)out_size; (void)ws_size;
    const float* u      = (const float*)d_in[0];
    const float* v      = (const float*)d_in[1];
    const float* adj    = (const float*)d_in[2];
    const float* degree = (const float*)d_in[3];
    const float* uw     = (const float*)d_in[4];
    const float* vw     = (const float*)d_in[5];
    const float* bias   = (const float*)d_in[6];
    const int*   rp     = (const int*)d_in[7];
    u16*   ws  = (u16*)d_ws;     // [0,1MB): suT bf16; [1MB,2MB): svT bf16
    float* out = (float*)d_out;

    k_prep<<<dim3(128, 2), 256, 0, stream>>>(u, v, uw, vw, rp, ws);
    k_main<<<dim3(256, 2), 256, 0, stream>>>(adj, degree, bias, ws, out);
}